// Round 7
// baseline (183.607 us; speedup 1.0000x reference)
//
#include <hip/hip_runtime.h>
#include <hip/hip_bf16.h>
#include <stdint.h>

typedef __attribute__((ext_vector_type(8))) short bf16x8;
typedef __attribute__((ext_vector_type(4))) float f32x4;

#define MFMA16(a, b, c) __builtin_amdgcn_mfma_f32_16x16x32_bf16((a), (b), (c), 0, 0, 0)

__device__ __forceinline__ unsigned short f2bf(float f) {
  unsigned int u = __builtin_bit_cast(unsigned int, f);
  unsigned int r = (u + 0x7fffu + ((u >> 16) & 1u)) >> 16;
  return (unsigned short)r;
}

__device__ __forceinline__ void gload16(const unsigned short* g, unsigned short* lds_dst) {
  __builtin_amdgcn_global_load_lds(
      (const __attribute__((address_space(1))) unsigned int*)g,
      (__attribute__((address_space(3))) unsigned int*)lds_dst, 16, 0, 0);
}

// ---------------- f32 -> bf16 conversion ----------------
__global__ void cvt_f32_bf16(const float* __restrict__ in, unsigned short* __restrict__ out, long n) {
  long i = ((long)blockIdx.x * blockDim.x + threadIdx.x) * 4;
  long stride = (long)gridDim.x * blockDim.x * 4;
  for (; i < n; i += stride) {
    float4 v = *(const float4*)(in + i);
    ushort4 o;
    o.x = f2bf(v.x); o.y = f2bf(v.y); o.z = f2bf(v.z); o.w = f2bf(v.w);
    *(ushort4*)(out + i) = o;
  }
}

// -------- 128x128 B^T GEMM: small-tile async-TLP (m97-fixed) --------
// 256 threads = 4 waves (2M x 2N), per-wave 64x64, BK=32 (one MFMA K-step).
// LDS only 32 KB (2buf x (A 128x32 + B 128x32) bf16) + VGPR cap 128
// (__launch_bounds__(256,4)) -> up to 4 blocks/CU CO-RESIDENT. The TLP is the
// mechanism (m114): no cross-block barriers, so one block's MFMA phase hides
// another block's LDS-read/stage/barrier phase. 1-block/CU lockstep designs
// (r1-r6) pinned at 23-25% MfmaUtil because LDS and MFMA pipes strictly
// alternate inside a barrier-locked block.
// Fixes vs r0 (same shape, 580 TF): XOR swizzle kills the 8-way read conflict
// (6.3M -> ~0), and double-buffer + counted vmcnt(4) (stage distance 2 K-steps,
// never drain-0 in the loop) replaces the single-buffer vmcnt(0) drain.
// Swizzle: LDS row = 64 B = 4 granules of 16 B; read granule = hi ^ (lo&3);
// staging source granule pre-swizzled ((l&3) ^ ((l>>2)&3)), LDS dest linear
// (rule 21). Bank spread: group = 4*(lo&1) + (hi^(lo&3)) -> 8 lanes per
// 4-bank group = the b128 floor, zero extra conflicts.
template <int EPI>
__global__ __launch_bounds__(256, 4)
void gemm_bt(const unsigned short* __restrict__ A,
             const unsigned short* __restrict__ Bt,
             const float* __restrict__ bias,
             int M, int N, int K,
             unsigned short* __restrict__ q_out,
             unsigned short* __restrict__ k_out,
             unsigned short* __restrict__ vt_out,
             float* __restrict__ f_out) {
  alignas(16) __shared__ unsigned short Abuf[2][128 * 32];  // 8 KB each
  alignas(16) __shared__ unsigned short Bbuf[2][128 * 32];
  const int t = threadIdx.x, w = t >> 6, l = t & 63;
  const int bm = blockIdx.x, bn = blockIdx.y;
  const int wm = w >> 1, wn = w & 1;
  const int lo = l & 15, hi = l >> 4, swk = lo & 3;

  f32x4 acc[4][4];
  const f32x4 zero = {0.f, 0.f, 0.f, 0.f};
#pragma unroll
  for (int i = 0; i < 4; ++i)
#pragma unroll
    for (int j = 0; j < 4; ++j) acc[i][j] = zero;

  // staging: wave w covers rows w*16..w*16+15 (and +64); lane l -> row
  // w*16+(l>>2), granule l&3; source granule inverse-swizzled by row&3.
  const int srA = w * 16 + (l >> 2);
  const int gsrcE = ((l & 3) ^ ((l >> 2) & 3)) * 8;  // bf16 elems
  const unsigned short* Asrc = A + (long)(bm * 128 + srA) * K + gsrcE;
  const unsigned short* Bsrc = Bt + (long)(bn * 128 + srA) * K + gsrcE;

#define STAGE(sb, koff) do {                                   \
    unsigned short* da_ = &Abuf[sb][w * 512];                  \
    unsigned short* db_ = &Bbuf[sb][w * 512];                  \
    gload16(Asrc + (koff), da_);                               \
    gload16(Asrc + 64L * K + (koff), da_ + 2048);              \
    gload16(Bsrc + (koff), db_);                               \
    gload16(Bsrc + 64L * K + (koff), db_ + 2048); } while (0)

  // prologue: stage K-steps 0 and 1
  STAGE(0, 0);
  STAGE(1, 32);

  // frag read geometry: row = (wm|wn)*64 + i*16 + lo (row&3 == lo&3),
  // granule (hi ^ swk)
  const int lrA = (wm * 64 + lo) * 32;
  const int lrB = (wn * 64 + lo) * 32;
  const int gk = (hi ^ swk) * 8;

  const int NKT = K >> 5;   // 32 for K=1024
  for (int kt = 0; kt < NKT; ++kt) {
    const int cur = kt & 1;
    // wait for stage(kt) (issued 2 steps ago); keep stage(kt+1) in flight
    if (kt == NKT - 1) { asm volatile("s_waitcnt vmcnt(0)" ::: "memory"); }
    else               { asm volatile("s_waitcnt vmcnt(4)" ::: "memory"); }
    __builtin_amdgcn_sched_barrier(0);
    __builtin_amdgcn_s_barrier();            // all waves' stage(kt) landed

    bf16x8 af[4], bfr[4];
#pragma unroll
    for (int i = 0; i < 4; ++i)
      af[i] = *(const bf16x8*)&Abuf[cur][lrA + i * 512 + gk];
#pragma unroll
    for (int j = 0; j < 4; ++j)
      bfr[j] = *(const bf16x8*)&Bbuf[cur][lrB + j * 512 + gk];
    asm volatile("s_waitcnt lgkmcnt(0)" ::: "memory");
    __builtin_amdgcn_sched_barrier(0);
    __builtin_amdgcn_s_barrier();            // all reads done -> buffer free

    if (kt + 2 < NKT) STAGE(cur, (kt + 2) * 32);  // refill freed buffer

    __builtin_amdgcn_s_setprio(1);
#pragma unroll
    for (int i = 0; i < 4; ++i)
#pragma unroll
      for (int j = 0; j < 4; ++j)
        acc[i][j] = MFMA16(af[i], bfr[j], acc[i][j]);
    __builtin_amdgcn_s_setprio(0);
  }
#undef STAGE

  // ---- epilogue ----
#pragma unroll
  for (int i = 0; i < 4; ++i) {
#pragma unroll
    for (int j = 0; j < 4; ++j) {
#pragma unroll
      for (int r = 0; r < 4; ++r) {
        int row = bm * 128 + wm * 64 + i * 16 + hi * 4 + r;
        int col = bn * 128 + wn * 64 + j * 16 + lo;
        float v = acc[i][j][r] + bias[col];
        if (EPI == 0) {
          int b = row >> 11, tt = row & 2047;
          int seg = col >> 10, cc = col & 1023;
          int h = cc >> 6, d = cc & 63;
          long bh = (long)(b * 16 + h);
          // Q pre-scaled by 1/sqrt(64) * log2(e) (softmax runs in exp2 domain)
          if (seg == 0)      q_out[(bh * 2048 + tt) * 64 + d] = f2bf(v * 0.1803368801111f);
          else if (seg == 1) k_out[(bh * 2048 + tt) * 64 + d] = f2bf(v);
          else               vt_out[(bh * 64 + d) * 2048 + tt] = f2bf(v);
        } else {
          f_out[(long)row * N + col] = v;
        }
      }
    }
  }
}

// ---------------- causal flash attention v6: max-free softmax (unchanged) ----------------
__global__ __launch_bounds__(512, 4)
void attn_kernel(const unsigned short* __restrict__ Q,
                 const unsigned short* __restrict__ K,
                 const unsigned short* __restrict__ Vt,
                 unsigned short* __restrict__ Y) {
  alignas(16) __shared__ unsigned short Kbuf[2][64 * 64];
  alignas(16) __shared__ unsigned short Vbuf[2][64 * 64];
  alignas(16) __shared__ unsigned short pbuf[8][16 * 64];
  const int t = threadIdx.x, w = t >> 6, l = t & 63;
  const int lo = l & 15, hi = l >> 4;
  const int bh = blockIdx.x;
  const int p = blockIdx.y;
  const int b = bh >> 4, h = bh & 15;
  const int sA = p, sB = 15 - p;
  const int nA = 2 * p + 2;
  const int nTot = 34;
  const unsigned short* Qp = Q + (long)bh * 2048 * 64;
  const unsigned short* Kp = K + (long)bh * 2048 * 64;
  const unsigned short* Vp = Vt + (long)bh * 64 * 2048;
  unsigned short* pw = pbuf[w];

  const short one_bf = (short)0x3F80;
  const bf16x8 ones = {one_bf, one_bf, one_bf, one_bf, one_bf, one_bf, one_bf, one_bf};
  const f32x4 zero = {0.f, 0.f, 0.f, 0.f};

  const int qbA = sA * 128 + w * 16;
  const int qbB = sB * 128 + w * 16;

  bf16x8 qf0, qf1;
  f32x4 lsum;
  f32x4 oacc[4];

  qf0 = *(const bf16x8*)&Qp[(qbA + lo) * 64 + hi * 8];
  qf1 = *(const bf16x8*)&Qp[(qbA + lo) * 64 + 32 + hi * 8];
  lsum = zero;
#pragma unroll
  for (int dg = 0; dg < 4; ++dg) oacc[dg] = zero;

  const int srow = t >> 3;
  const int scw = ((t & 7) ^ (srow & 7)) * 8;
  const int sw = lo & 7;

#define STAGE(kvoff, bufidx)                                          \
  do {                                                                \
    unsigned short* KB_ = Kbuf[bufidx] + w * 512;                     \
    unsigned short* VB_ = Vbuf[bufidx] + w * 512;                     \
    gload16(Kp + (long)((kvoff) + srow) * 64 + scw, KB_);             \
    gload16(Vp + (long)srow * 2048 + (kvoff) + scw, VB_);             \
  } while (0)

  STAGE(0, 0);
  __syncthreads();

  for (int g = 0; g < nTot; ++g) {
    const bool inA = (g < nA);
    const int kvb = (inA ? g : g - nA) * 64;
    const int cur = g & 1;
    if (g + 1 < nTot) {
      const int jn = (g + 1 < nA) ? g + 1 : g + 1 - nA;
      STAGE(jn * 64, cur ^ 1);
    }
    const int qbase = inA ? qbA : qbB;
    if (kvb <= qbase + 15) {
      const unsigned short* KB = Kbuf[cur];
      const unsigned short* VB = Vbuf[cur];
      f32x4 s[4];
#pragma unroll
      for (int cg = 0; cg < 4; ++cg) s[cg] = zero;
      __builtin_amdgcn_s_setprio(1);
#pragma unroll
      for (int cg = 0; cg < 4; ++cg) {
        bf16x8 k0 = *(const bf16x8*)&KB[(cg * 16 + lo) * 64 + ((hi) ^ sw) * 8];
        bf16x8 k1 = *(const bf16x8*)&KB[(cg * 16 + lo) * 64 + ((4 + hi) ^ sw) * 8];
        s[cg] = MFMA16(k0, qf0, s[cg]);
        s[cg] = MFMA16(k1, qf1, s[cg]);
      }
      __builtin_amdgcn_s_setprio(0);
      if (kvb + 63 > qbase) {
        const int limit = qbase + lo - kvb;
#pragma unroll
        for (int cg = 0; cg < 4; ++cg)
#pragma unroll
          for (int r = 0; r < 4; ++r)
            if (cg * 16 + hi * 4 + r > limit) s[cg][r] = -__builtin_inff();
      }
      // max-free softmax numerator: p = exp2(s)
#pragma unroll
      for (int cg = 0; cg < 4; ++cg) {
        float p0 = exp2f(s[cg][0]);
        float p1 = exp2f(s[cg][1]);
        float p2 = exp2f(s[cg][2]);
        float p3 = exp2f(s[cg][3]);
        unsigned int u0, u1;
        asm("v_cvt_pk_bf16_f32 %0, %1, %2" : "=v"(u0) : "v"(p0), "v"(p1));
        asm("v_cvt_pk_bf16_f32 %0, %1, %2" : "=v"(u1) : "v"(p2), "v"(p3));
        const int gg = (cg * 2 + (hi >> 1)) ^ sw;
        uint2 val; val.x = u0; val.y = u1;
        *(uint2*)&pw[lo * 64 + gg * 8 + (hi & 1) * 4] = val;
      }
      asm volatile("s_waitcnt lgkmcnt(0)" ::: "memory");
      bf16x8 pa0 = *(const bf16x8*)&pw[lo * 64 + ((hi) ^ sw) * 8];
      bf16x8 pa1 = *(const bf16x8*)&pw[lo * 64 + ((4 + hi) ^ sw) * 8];
      __builtin_amdgcn_s_setprio(1);
      lsum = MFMA16(pa0, ones, lsum);
      lsum = MFMA16(pa1, ones, lsum);
#pragma unroll
      for (int dg = 0; dg < 4; ++dg) {
        bf16x8 vv0 = *(const bf16x8*)&VB[(dg * 16 + lo) * 64 + ((hi) ^ sw) * 8];
        bf16x8 vv1 = *(const bf16x8*)&VB[(dg * 16 + lo) * 64 + ((4 + hi) ^ sw) * 8];
        oacc[dg] = MFMA16(pa0, vv0, oacc[dg]);
        oacc[dg] = MFMA16(pa1, vv1, oacc[dg]);
      }
      __builtin_amdgcn_s_setprio(0);
    }
    if (g == nA - 1) {
#pragma unroll
      for (int r = 0; r < 4; ++r) {
        float inv = 1.0f / lsum[r];
        int rowg = qbA + hi * 4 + r;
        long base = ((long)b * 2048 + rowg) * 1024 + h * 64;
#pragma unroll
        for (int dg = 0; dg < 4; ++dg)
          Y[base + dg * 16 + lo] = f2bf(oacc[dg][r] * inv);
      }
      qf0 = *(const bf16x8*)&Qp[(qbB + lo) * 64 + hi * 8];
      qf1 = *(const bf16x8*)&Qp[(qbB + lo) * 64 + 32 + hi * 8];
      lsum = zero;
#pragma unroll
      for (int dg = 0; dg < 4; ++dg) oacc[dg] = zero;
    }
    __syncthreads();
  }

#pragma unroll
  for (int r = 0; r < 4; ++r) {
    float inv = 1.0f / lsum[r];
    int rowg = qbB + hi * 4 + r;
    long base = ((long)b * 2048 + rowg) * 1024 + h * 64;
#pragma unroll
    for (int dg = 0; dg < 4; ++dg)
      Y[base + dg * 16 + lo] = f2bf(oacc[dg][r] * inv);
  }
#undef STAGE
}

extern "C" void kernel_launch(void* const* d_in, const int* in_sizes, int n_in,
                              void* d_out, int out_size, void* d_ws, size_t ws_size,
                              hipStream_t stream) {
  const float* x      = (const float*)d_in[0];
  const float* w_attn = (const float*)d_in[1];
  const float* b_attn = (const float*)d_in[2];
  const float* w_proj = (const float*)d_in[3];
  const float* b_proj = (const float*)d_in[4];
  float* out = (float*)d_out;

  const long NX = 8192L * 1024;
  const long NWA = 3072L * 1024;
  const long NWP = 1024L * 1024;
  const long NQ = 64L * 2048 * 64;

  char* ws = (char*)d_ws;
  unsigned short* xb  = (unsigned short*)ws; ws += NX * 2;
  unsigned short* wab = (unsigned short*)ws; ws += NWA * 2;
  unsigned short* wpb = (unsigned short*)ws; ws += NWP * 2;
  unsigned short* qb  = (unsigned short*)ws; ws += NQ * 2;
  unsigned short* kb  = (unsigned short*)ws; ws += NQ * 2;
  unsigned short* vtb = (unsigned short*)ws; ws += NQ * 2;
  unsigned short* yb  = (unsigned short*)ws; ws += NX * 2;

  cvt_f32_bf16<<<2048, 256, 0, stream>>>(x, xb, NX);
  cvt_f32_bf16<<<768, 256, 0, stream>>>(w_attn, wab, NWA);
  cvt_f32_bf16<<<256, 256, 0, stream>>>(w_proj, wpb, NWP);

  dim3 g1(64, 24);   // 1536 blocks @ up to 4/CU co-resident (async TLP)
  gemm_bt<0><<<g1, 256, 0, stream>>>(xb, wab, b_attn, 8192, 3072, 1024,
                                     qb, kb, vtb, nullptr);
  dim3 ga(64, 8);
  attn_kernel<<<ga, 512, 0, stream>>>(qb, kb, vtb, yb);
  dim3 g2(64, 8);    // 512 blocks = 2/CU uniform
  gemm_bt<1><<<g2, 256, 0, stream>>>(yb, wpb, b_proj, 8192, 1024, 1024,
                                     nullptr, nullptr, nullptr, out);
}